// Round 1
// baseline (410.744 us; speedup 1.0000x reference)
//
#include <hip/hip_runtime.h>
#include <stdint.h>

// SpecAugment: out[b,t,f] = x[b,t,f] * keep(b,t,f)
// keep = !(freq_mask[f] | time_mask[b,t]), masks derived from JAX threefry2x32
// (seed 42), partitionable ("fold-like") counter scheme (JAX >= 0.4.30 default).
//
// B=128, T=4000, F=128 (fixed by the reference setup_inputs).

#define B_DIM 128
#define T_DIM 4000
#define F_DIM 128

__device__ __forceinline__ uint32_t rotl32(uint32_t x, uint32_t d) {
  return (x << d) | (x >> (32u - d));
}

// JAX threefry2x32 block cipher (20 rounds).
__device__ __forceinline__ void threefry2x32(uint32_t k0, uint32_t k1,
                                             uint32_t x0, uint32_t x1,
                                             uint32_t& y0, uint32_t& y1) {
  const uint32_t ks[3] = {k0, k1, k0 ^ k1 ^ 0x1BD11BDAu};
  const uint32_t rotA[4] = {13u, 15u, 26u, 6u};
  const uint32_t rotB[4] = {17u, 29u, 16u, 24u};
  x0 += ks[0];
  x1 += ks[1];
#pragma unroll
  for (int i = 0; i < 5; ++i) {
#pragma unroll
    for (int j = 0; j < 4; ++j) {
      const uint32_t r = (i & 1) ? rotB[j] : rotA[j];
      x0 += x1;
      x1 = rotl32(x1, r);
      x1 ^= x0;
    }
    x0 += ks[(i + 1) % 3];
    x1 += ks[(i + 2) % 3] + (uint32_t)(i + 1);
  }
  y0 = x0;
  y1 = x1;
}

// Partitionable random bits: element index e -> xor of cipher outputs at
// 64-bit counter e (hi=0 for our sizes).
__device__ __forceinline__ uint32_t rbits(uint32_t k0, uint32_t k1, uint32_t e) {
  uint32_t y0, y1;
  threefry2x32(k0, k1, 0u, e, y0, y1);
  return y0 ^ y1;
}

// JAX uniform [0,1): bitcast((bits >> 9) | 0x3f800000) - 1.0f
__device__ __forceinline__ float u01(uint32_t bits) {
  const uint32_t fb = (bits >> 9) | 0x3f800000u;
  return __fsub_rn(__uint_as_float(fb), 1.0f);
}

// One block, 128 threads (thread b = batch index = frequency bin index).
// ws layout (floats): [0..127]   keepF[f]  (1.0 keep / 0.0 masked)
//                     [128..639] per-b float4 {ts0, te0, ts1, te1}
__global__ __launch_bounds__(128) void specaug_setup(
    const int* __restrict__ x_len, float* __restrict__ ws) {
  const int b = threadIdx.x;

  // split(key(42), 3) fold-like: key_i = cipher((0,42),(0,i))
  uint32_t kf0, kf1, kv0, kv1, ks0, ks1;
  threefry2x32(0u, 42u, 0u, 0u, kf0, kf1);
  threefry2x32(0u, 42u, 0u, 1u, kv0, kv1);
  threefry2x32(0u, 42u, 0u, 2u, ks0, ks1);

  // ---- frequency masks (shared across batch); thread b handles bin f=b ----
  // uf = uniform(kf, (2,2)) row-major: elements 0..3
  const float uf00 = u01(rbits(kf0, kf1, 0u));
  const float uf01 = u01(rbits(kf0, kf1, 1u));
  const float uf10 = u01(rbits(kf0, kf1, 2u));
  const float uf11 = u01(rbits(kf0, kf1, 3u));

  const float fv0 = __fmul_rn(uf00, 27.0f);
  const float fst0 = __fmul_rn(uf01, __fsub_rn(128.0f, fv0));
  const float fS0 = floorf(fst0);
  const float fE0 = floorf(__fadd_rn(fst0, fv0));

  const float fv1 = __fmul_rn(uf10, 27.0f);
  const float fst1 = __fmul_rn(uf11, __fsub_rn(128.0f, fv1));
  const float fS1 = floorf(fst1);
  const float fE1 = floorf(__fadd_rn(fst1, fv1));

  const float ff = (float)b;
  const bool fmask = (ff >= fS0 && ff < fE0) || (ff >= fS1 && ff < fE1);
  ws[b] = fmask ? 0.0f : 1.0f;

  // ---- time masks, per-sample adaptive ----
  const float xl = (float)x_len[b];
  const float tparam = floorf(__fmul_rn(0.25f, xl));

  // uv = uniform(kv, (128,2)), us = uniform(ks, (128,2)); element e = 2b+m
  const float uv0 = u01(rbits(kv0, kv1, (uint32_t)(2 * b)));
  const float uv1 = u01(rbits(kv0, kv1, (uint32_t)(2 * b + 1)));
  const float us0 = u01(rbits(ks0, ks1, (uint32_t)(2 * b)));
  const float us1 = u01(rbits(ks0, ks1, (uint32_t)(2 * b + 1)));

  const float tv0 = __fmul_rn(uv0, tparam);
  const float tst0 = __fmul_rn(us0, __fsub_rn(xl, tv0));
  const float TS0 = floorf(tst0);
  const float TE0 = floorf(__fadd_rn(tst0, tv0));

  const float tv1 = __fmul_rn(uv1, tparam);
  const float tst1 = __fmul_rn(us1, __fsub_rn(xl, tv1));
  const float TS1 = floorf(tst1);
  const float TE1 = floorf(__fadd_rn(tst1, tv1));

  float4* tse = (float4*)(ws + F_DIM);
  tse[b] = make_float4(TS0, TE0, TS1, TE1);
}

// Streaming apply: 8 rows (b,t) per block, 32 lanes x float4 covering F=128.
__global__ __launch_bounds__(256) void specaug_apply(
    const float* __restrict__ x, const float* __restrict__ ws,
    float* __restrict__ out) {
  const int tid = threadIdx.x;
  const int lane = tid & 31;          // float4 index along F
  const int row_in_blk = tid >> 5;    // 0..7
  const uint32_t r = blockIdx.x * 8u + (uint32_t)row_in_blk;  // row in [0, B*T)
  const uint32_t b = r / (uint32_t)T_DIM;
  const uint32_t t = r - b * (uint32_t)T_DIM;

  const float tf = (float)t;
  const float4 tse = ((const float4*)(ws + F_DIM))[b];
  const bool tmask = (tf >= tse.x && tf < tse.y) || (tf >= tse.z && tf < tse.w);

  const float4 fk = ((const float4*)ws)[lane];
  const size_t off = (size_t)r * F_DIM + (size_t)lane * 4;
  const float4 v = *(const float4*)(x + off);

  float4 o;
  if (tmask) {
    o = make_float4(0.0f, 0.0f, 0.0f, 0.0f);
  } else {
    o.x = v.x * fk.x;
    o.y = v.y * fk.y;
    o.z = v.z * fk.z;
    o.w = v.w * fk.w;
  }
  *(float4*)(out + off) = o;
}

extern "C" void kernel_launch(void* const* d_in, const int* in_sizes, int n_in,
                              void* d_out, int out_size, void* d_ws, size_t ws_size,
                              hipStream_t stream) {
  const float* x = (const float*)d_in[0];
  const int* x_len = (const int*)d_in[1];
  float* out = (float*)d_out;
  float* ws = (float*)d_ws;

  specaug_setup<<<1, B_DIM, 0, stream>>>(x_len, ws);

  const int rows = B_DIM * T_DIM;          // 512000
  const int blocks = rows / 8;             // 64000
  specaug_apply<<<blocks, 256, 0, stream>>>(x, ws, out);
}